// Round 10
// baseline (189.112 us; speedup 1.0000x reference)
//
#include <hip/hip_runtime.h>

typedef __bf16 bf16x8 __attribute__((ext_vector_type(8)));
typedef float f32x4 __attribute__((ext_vector_type(4)));
typedef float f32x16 __attribute__((ext_vector_type(16)));
typedef unsigned int uint2v __attribute__((ext_vector_type(2)));

#define LOG2E 1.44269504088896340736f

#if __has_builtin(__builtin_amdgcn_exp2f)
#define EXP2(x) __builtin_amdgcn_exp2f(x)
#else
#define EXP2(x) exp2f(x)
#endif

static __device__ __forceinline__ unsigned short f2bf(float f) {
    unsigned int u = __builtin_bit_cast(unsigned int, f);
    u += 0x7fffu + ((u >> 16) & 1u);   // RNE
    return (unsigned short)(u >> 16);
}

static __device__ __forceinline__ void plswap(unsigned int& a, unsigned int& b) {
#if __has_builtin(__builtin_amdgcn_permlane32_swap)
    uint2v r = __builtin_amdgcn_permlane32_swap(a, b, false, false);
    a = r.x; b = r.y;
#else
    asm("v_permlane32_swap_b32 %0, %1" : "+v"(a), "+v"(b));
#endif
}

static __device__ __forceinline__ float xhalf_add(float x) {
    unsigned int a = __builtin_bit_cast(unsigned int, x), b = a;
    plswap(a, b);
    return __builtin_bit_cast(float, a) + __builtin_bit_cast(float, b);
}

// ---------------- fp32 -> bf16 convert ----------------
__global__ void cvt_kernel(const float* __restrict__ in, unsigned short* __restrict__ out, int n4) {
    int i = blockIdx.x * blockDim.x + threadIdx.x;
    int stride = gridDim.x * blockDim.x;
    for (; i < n4; i += stride) {
        float4 v = reinterpret_cast<const float4*>(in)[i];
        ushort4 o;
        o.x = f2bf(v.x); o.y = f2bf(v.y); o.z = f2bf(v.z); o.w = f2bf(v.w);
        reinterpret_cast<ushort4*>(out)[i] = o;
    }
}

// ---------------- counted-vmcnt phase-pipelined bf16 GEMM, C = A * B^T (+bias) ----------------
// BM=128, BN=256, BK=64 as two k=32 slices (the phase unit). 512 thr, 8 waves (2Mx4N),
// wave tile 64x64 (acc 4x4). LDS: 2 bufs x 2 slices x (A 8KB + B 16KB) = 96 KB.
// Phase (t,s): vmcnt(3) [counted: other slice stays in flight] -> raw s_barrier ->
// stage slice s of tile t+1 (3 global_load_lds, full-phase cover) -> 8 swizzled
// ds_reads -> setprio(1) 16 MFMA setprio(0). No vmcnt(0) until the last phase.
// Swizzle: chunk ^= (row&3) ^ ((row>>2)&3), applied on global source AND ds_read.
// MODE 0: QKV scatter (Q scaled 0.125*log2e; V via single-pass LDS-bounce).
// MODE 1: fp32 C + bias.
template <int MODE>
__global__ __launch_bounds__(512, 2) void gemm256(const unsigned short* __restrict__ A,
                                                  const unsigned short* __restrict__ B,
                                                  const float* __restrict__ bias,
                                                  void* __restrict__ Cout,
                                                  int M, int N, int K, int nbx) {
    __shared__ unsigned short SMEM[49152];   // 96 KB
    // A chunks: [buf][s] at buf*8192 + s*4096 (128x32 shorts)
    // B chunks: [buf][s] at 16384 + buf*16384 + s*8192 (256x32 shorts)

    const int tid = threadIdx.x;
    const int w = tid >> 6, lane = tid & 63;
    const int wr = w >> 2, wc = w & 3;
    const int l15 = lane & 15, l4 = lane >> 4;

    const int cpx = gridDim.x >> 3;
    const int swzb = (blockIdx.x & 7) * cpx + (blockIdx.x >> 3);
    const int bx = swzb % nbx, by = swzb / nbx;
    const int bm0 = by << 7, bn0 = bx << 8;

    const int strow = tid >> 2;       // staging row within 128-row group
    const int stc = tid & 3;          // linear dest chunk

    f32x4 acc[4][4] = {};

    auto stage_slice = [&](int buf, int kt, int s) {
        const int k0 = (kt << 6) + s * 32;
        {
            int row = strow;                                   // A: 128 rows, 1 instr
            int c = stc ^ (row & 3) ^ ((row >> 2) & 3);
            const unsigned short* g = A + (size_t)(bm0 + row) * K + k0 + c * 8;
            __builtin_amdgcn_global_load_lds(
                (const __attribute__((address_space(1))) void*)g,
                (__attribute__((address_space(3))) void*)&SMEM[buf * 8192 + s * 4096 + tid * 8],
                16, 0, 0);
        }
        #pragma unroll
        for (int i = 0; i < 2; ++i) {                          // B: 256 rows, 2 instr
            int row = i * 128 + strow;
            int c = stc ^ (row & 3) ^ ((row >> 2) & 3);
            const unsigned short* g = B + (size_t)(bn0 + row) * K + k0 + c * 8;
            __builtin_amdgcn_global_load_lds(
                (const __attribute__((address_space(1))) void*)g,
                (__attribute__((address_space(3))) void*)&SMEM[16384 + buf * 16384 + s * 8192 + i * 4096 + tid * 8],
                16, 0, 0);
        }
    };

    const int nk = K >> 6;            // 16
    stage_slice(0, 0, 0);
    stage_slice(0, 0, 1);

    const int rA0 = wr * 64 + l15;
    const int rB0 = wc * 64 + l15;

    for (int kt = 0; kt < nk; ++kt) {
        const int p = kt & 1;
        #pragma unroll
        for (int s = 0; s < 2; ++s) {
            if (kt == nk - 1 && s == 1) {
                asm volatile("s_waitcnt vmcnt(0)" ::: "memory");
            } else {
                asm volatile("s_waitcnt vmcnt(3)" ::: "memory");
            }
            __builtin_amdgcn_s_barrier();
            __builtin_amdgcn_sched_barrier(0);
            if (kt + 1 < nk) stage_slice(p ^ 1, kt + 1, s);

            bf16x8 af[4], bfr[4];
            #pragma unroll
            for (int fr = 0; fr < 4; ++fr) {
                int row = rA0 + fr * 16;
                int c = l4 ^ (row & 3) ^ ((row >> 2) & 3);
                af[fr] = *(const bf16x8*)&SMEM[p * 8192 + s * 4096 + row * 32 + c * 8];
            }
            #pragma unroll
            for (int nj = 0; nj < 4; ++nj) {
                int row = rB0 + nj * 16;
                int c = l4 ^ (row & 3) ^ ((row >> 2) & 3);
                bfr[nj] = *(const bf16x8*)&SMEM[16384 + p * 16384 + s * 8192 + row * 32 + c * 8];
            }
            __builtin_amdgcn_s_setprio(1);
            #pragma unroll
            for (int fr = 0; fr < 4; ++fr)
                #pragma unroll
                for (int nj = 0; nj < 4; ++nj)
                    acc[fr][nj] = __builtin_amdgcn_mfma_f32_16x16x32_bf16(af[fr], bfr[nj], acc[fr][nj], 0, 0, 0);
            __builtin_amdgcn_s_setprio(0);
            __builtin_amdgcn_sched_barrier(0);
        }
    }
    __syncthreads();   // full drain; safe LDS reuse below

    if (MODE == 0) {
        unsigned short* O = (unsigned short*)Cout;
        if (bn0 >= 2048) {
            // V region: single-pass LDS transpose bounce -> coalesced uint4 stores
            unsigned short* T = &SMEM[0];    // T[cl 0..255][nl 0..127], stride 136
            #pragma unroll
            for (int nj = 0; nj < 4; ++nj) {
                int cl = wc * 64 + nj * 16 + l15;
                float bv = bias[bn0 + cl];
                #pragma unroll
                for (int fr = 0; fr < 4; ++fr) {
                    int nl = wr * 64 + fr * 16 + l4 * 4;
                    ushort4 pk;
                    pk.x = f2bf(acc[fr][nj][0] + bv);
                    pk.y = f2bf(acc[fr][nj][1] + bv);
                    pk.z = f2bf(acc[fr][nj][2] + bv);
                    pk.w = f2bf(acc[fr][nj][3] + bv);
                    *(ushort4*)&T[cl * 136 + nl] = pk;
                }
            }
            __syncthreads();
            const int b = bm0 >> 11, n0 = bm0 & 2047;
            #pragma unroll
            for (int it = 0; it < 8; ++it) {
                int flat = it * 512 + tid;
                int cl = flat >> 4, ch = flat & 15;
                uint4 val = *(const uint4*)&T[cl * 136 + ch * 8];
                int col = bn0 + cl;
                int h = (col >> 6) & 15, d = col & 63;
                size_t idx = (size_t)16777216 +
                             ((size_t)((b * 16 + h) * 64 + d)) * 2048 + n0 + ch * 8;
                *(uint4*)&O[idx] = val;
            }
        } else {
            #pragma unroll
            for (int nj = 0; nj < 4; ++nj) {
                int col = bn0 + wc * 64 + nj * 16 + l15;
                float bv = bias[col];
                int which = col >> 10;
                int h = (col >> 6) & 15, d = col & 63;
                float scale = (which == 0) ? 0.125f * LOG2E : 1.0f;
                size_t base = (which == 0) ? (size_t)0 : (size_t)8388608;
                #pragma unroll
                for (int fr = 0; fr < 4; ++fr) {
                    #pragma unroll
                    for (int r = 0; r < 4; ++r) {
                        int row = bm0 + wr * 64 + fr * 16 + l4 * 4 + r;
                        int b = row >> 11, n = row & 2047;
                        float v = (acc[fr][nj][r] + bv) * scale;
                        O[base + ((size_t)((b * 16 + h) * 2048 + n)) * 64 + d] = f2bf(v);
                    }
                }
            }
        }
    } else {
        float* C = (float*)Cout;
        #pragma unroll
        for (int nj = 0; nj < 4; ++nj) {
            int col = bn0 + wc * 64 + nj * 16 + l15;
            float bv = bias[col];
            #pragma unroll
            for (int fr = 0; fr < 4; ++fr) {
                #pragma unroll
                for (int r = 0; r < 4; ++r) {
                    int row = bm0 + wr * 64 + fr * 16 + l4 * 4 + r;
                    C[(size_t)row * N + col] = acc[fr][nj][r] + bv;
                }
            }
        }
    }
}

// ---------------- flash attention v7: 64 q/wave, no online max (unchanged r9) ----------------
__global__ __launch_bounds__(256, 2) void attn_kernel(const unsigned short* __restrict__ qkv,
                                                      unsigned short* __restrict__ out) {
    __shared__ unsigned short Klds[2][4096];
    __shared__ unsigned short Vlds[2][4096];

    const int tid = threadIdx.x;
    const int w = tid >> 6, lane = tid & 63;
    const int ql = lane & 31;
    const int hi = lane >> 5;
    const int id = blockIdx.x;
    const int bh = id & 63;
    const int qt = id >> 6;
    const size_t SEC = 8388608;

    const unsigned short* Q  = qkv + (size_t)bh * (2048 * 64);
    const unsigned short* Kp = qkv + SEC + (size_t)bh * (2048 * 64);
    const unsigned short* Vt = qkv + 2 * SEC + (size_t)bh * (64 * 2048);

    const int q0 = qt * 256 + w * 64;

    bf16x8 qbA[4], qbB[4];
    #pragma unroll
    for (int c = 0; c < 4; ++c) {
        qbA[c] = *(const bf16x8*)&Q[(size_t)(q0 + ql) * 64 + c * 16 + hi * 8];
        qbB[c] = *(const bf16x8*)&Q[(size_t)(q0 + 32 + ql) * 64 + c * 16 + hi * 8];
    }

    f32x16 oA0 = {}, oA1 = {}, oB0 = {}, oB1 = {};
    float lsA = 0.f, lsB = 0.f;

    const int sri = lane >> 3;
    const int sch = lane & 7;

    auto stage = [&](int buf, int tile) {
        const int kb = tile * 64;
        #pragma unroll
        for (int i = 0; i < 2; ++i) {
            const int r = w * 16 + i * 8 + sri;
            const int c = sch ^ (r & 7);
            const unsigned short* gk = Kp + (size_t)(kb + r) * 64 + c * 8;
            __builtin_amdgcn_global_load_lds(
                (const __attribute__((address_space(1))) void*)gk,
                (__attribute__((address_space(3))) void*)&Klds[buf][w * 1024 + i * 512],
                16, 0, 0);
            const unsigned short* gv = Vt + (size_t)r * 2048 + kb + c * 8;
            __builtin_amdgcn_global_load_lds(
                (const __attribute__((address_space(1))) void*)gv,
                (__attribute__((address_space(3))) void*)&Vlds[buf][w * 1024 + i * 512],
                16, 0, 0);
        }
    };

    auto softmax_block = [&](f32x16& s0, f32x16& s1, float& lsum,
                             bf16x8 (&p0)[2], bf16x8 (&p1)[2]) {
        #pragma unroll
        for (int r = 0; r < 16; ++r) s0[r] = EXP2(s0[r]);
        #pragma unroll
        for (int r = 0; r < 16; ++r) s1[r] = EXP2(s1[r]);
        float u0 = ((s0[0] + s0[1]) + (s0[2] + s0[3])) + ((s0[4] + s0[5]) + (s0[6] + s0[7]));
        float u1 = ((s0[8] + s0[9]) + (s0[10] + s0[11])) + ((s0[12] + s0[13]) + (s0[14] + s0[15]));
        float u2 = ((s1[0] + s1[1]) + (s1[2] + s1[3])) + ((s1[4] + s1[5]) + (s1[6] + s1[7]));
        float u3 = ((s1[8] + s1[9]) + (s1[10] + s1[11])) + ((s1[12] + s1[13]) + (s1[14] + s1[15]));
        float rs = (u0 + u1) + (u2 + u3);
        lsum += xhalf_add(rs);
        #pragma unroll
        for (int g = 0; g < 2; ++g) {
            unsigned int x0, x1, x2, x3;
            asm("v_cvt_pk_bf16_f32 %0, %1, %2" : "=v"(x0) : "v"(s0[8*g + 0]), "v"(s0[8*g + 1]));
            asm("v_cvt_pk_bf16_f32 %0, %1, %2" : "=v"(x1) : "v"(s0[8*g + 2]), "v"(s0[8*g + 3]));
            asm("v_cvt_pk_bf16_f32 %0, %1, %2" : "=v"(x2) : "v"(s0[8*g + 4]), "v"(s0[8*g + 5]));
            asm("v_cvt_pk_bf16_f32 %0, %1, %2" : "=v"(x3) : "v"(s0[8*g + 6]), "v"(s0[8*g + 7]));
            plswap(x0, x2);
            plswap(x1, x3);
            uint4 wds; wds.x = x0; wds.y = x1; wds.z = x2; wds.w = x3;
            p0[g] = __builtin_bit_cast(bf16x8, wds);
        }
        #pragma unroll
        for (int g = 0; g < 2; ++g) {
            unsigned int x0, x1, x2, x3;
            asm("v_cvt_pk_bf16_f32 %0, %1, %2" : "=v"(x0) : "v"(s1[8*g + 0]), "v"(s1[8*g + 1]));
            asm("v_cvt_pk_bf16_f32 %0, %1, %2" : "=v"(x1) : "v"(s1[8*g + 2]), "v"(s1[8*g + 3]));
            asm("v_cvt_pk_bf16_f32 %0, %1, %2" : "=v"(x2) : "v"(s1[8*g + 4]), "v"(s1[8*g + 5]));
            asm("v_cvt_pk_bf16_f32 %0, %1, %2" : "=v"(x3) : "v"(s1[8*g + 6]), "v"(s1[8*g + 7]));
            plswap(x0, x2);
            plswap(x1, x3);
            uint4 wds; wds.x = x0; wds.y = x1; wds.z = x2; wds.w = x3;
            p1[g] = __builtin_bit_cast(bf16x8, wds);
        }
    };

    stage(0, 0);
    __syncthreads();

    for (int t = 0; t < 32; ++t) {
        const int cur = t & 1;
        if (t + 1 < 32) stage(cur ^ 1, t + 1);

        bf16x8 k0[4], k1[4];
        #pragma unroll
        for (int mf = 0; mf < 4; ++mf) {
            int c0 = ((mf * 2 + hi) ^ (ql & 7));
            k0[mf] = *(const bf16x8*)&Klds[cur][ql * 64 + c0 * 8];
            k1[mf] = *(const bf16x8*)&Klds[cur][(32 + ql) * 64 + c0 * 8];
        }

        f32x16 sA0 = {}, sA1 = {};
        #pragma unroll
        for (int mf = 0; mf < 4; ++mf)
            sA0 = __builtin_amdgcn_mfma_f32_32x32x16_bf16(k0[mf], qbA[mf], sA0, 0, 0, 0);
        #pragma unroll
        for (int mf = 0; mf < 4; ++mf)
            sA1 = __builtin_amdgcn_mfma_f32_32x32x16_bf16(k1[mf], qbA[mf], sA1, 0, 0, 0);
        f32x16 sB0 = {}, sB1 = {};
        #pragma unroll
        for (int mf = 0; mf < 4; ++mf)
            sB0 = __builtin_amdgcn_mfma_f32_32x32x16_bf16(k0[mf], qbB[mf], sB0, 0, 0, 0);
        #pragma unroll
        for (int mf = 0; mf < 4; ++mf)
            sB1 = __builtin_amdgcn_mfma_f32_32x32x16_bf16(k1[mf], qbB[mf], sB1, 0, 0, 0);

        bf16x8 v0[4], v1[4];
        #pragma unroll
        for (int ks = 0; ks < 4; ++ks) {
            int c0 = ((ks * 2 + hi) ^ (ql & 7));
            v0[ks] = *(const bf16x8*)&Vlds[cur][ql * 64 + c0 * 8];
            v1[ks] = *(const bf16x8*)&Vlds[cur][(32 + ql) * 64 + c0 * 8];
        }

        bf16x8 pA0[2], pA1[2], pB0[2], pB1[2];
        softmax_block(sA0, sA1, lsA, pA0, pA1);
        softmax_block(sB0, sB1, lsB, pB0, pB1);

        oA0 = __builtin_amdgcn_mfma_f32_32x32x16_bf16(v0[0], pA0[0], oA0, 0, 0, 0);
        oA0 = __builtin_amdgcn_mfma_f32_32x32x16_bf16(v0[1], pA0[1], oA0, 0, 0, 0);
        oA0 = __builtin_amdgcn_mfma_f32_32x32x16_bf16(v0[2], pA1[0], oA0, 0, 0, 0);
        oA0 = __builtin_amdgcn_mfma_f32_32x32x16_bf16(v0[3], pA1[1], oA0, 0, 0, 0);
        oA1 = __builtin_amdgcn_mfma_f32_32x32x16_bf16(v1[0], pA0[0], oA1, 0, 0, 0);
        oA1 = __builtin_amdgcn_mfma_f32_32x32x16_bf16(v1[1], pA0[1], oA1, 0, 0, 0);
        oA1 = __builtin_amdgcn_mfma_f32_32x32x16_bf16(v1[2], pA1[0], oA1, 0, 0, 0);
        oA1 = __builtin_amdgcn_mfma_f32_32x32x16_bf16(v1[3], pA1[1], oA1, 0, 0, 0);
        oB0 = __builtin_amdgcn_mfma_f32_32x32x16_bf16(v0[0], pB0[0], oB0, 0, 0, 0);
        oB0 = __builtin_amdgcn_mfma_f32_32x32x16_bf16(v0[1], pB0[1], oB0, 0, 0, 0);
        oB0 = __builtin_amdgcn_mfma_f32_32x32x16_bf16(v0[2], pB1[0], oB0, 0, 0, 0);
        oB0 = __builtin_amdgcn_mfma_f32_32x32x16_bf16(v0[3], pB1[1], oB0, 0, 0, 0);
        oB1 = __builtin_amdgcn_mfma_f32_32x32x16_bf16(v1[0], pB0[0], oB1, 0, 0, 0);
        oB1 = __builtin_amdgcn_mfma_f32_32x32x16_bf16(v1[1], pB0[1], oB1, 0, 0, 0);
        oB1 = __builtin_amdgcn_mfma_f32_32x32x16_bf16(v1[2], pB1[0], oB1, 0, 0, 0);
        oB1 = __builtin_amdgcn_mfma_f32_32x32x16_bf16(v1[3], pB1[1], oB1, 0, 0, 0);

        __syncthreads();
    }

    const int b = bh >> 4, h = bh & 15;
    {
        const float inv = 1.0f / lsA;
        const int n = q0 + ql;
        unsigned short* obase = out + ((size_t)(b * 2048 + n)) * 1024 + h * 64;
        #pragma unroll
        for (int g = 0; g < 4; ++g) {
            int d0 = 8 * g + 4 * hi;
            ushort4 w0, w1;
            w0.x = f2bf(oA0[4 * g + 0] * inv);
            w0.y = f2bf(oA0[4 * g + 1] * inv);
            w0.z = f2bf(oA0[4 * g + 2] * inv);
            w0.w = f2bf(oA0[4 * g + 3] * inv);
            *(ushort4*)(obase + d0) = w0;
            w1.x = f2bf(oA1[4 * g + 0] * inv);
            w1.y = f2bf(oA1[4 * g + 1] * inv);
            w1.z = f2bf(oA1[4 * g + 2] * inv);
            w1.w = f2bf(oA1[4 * g + 3] * inv);
            *(ushort4*)(obase + 32 + d0) = w1;
        }
    }
    {
        const float inv = 1.0f / lsB;
        const int n = q0 + 32 + ql;
        unsigned short* obase = out + ((size_t)(b * 2048 + n)) * 1024 + h * 64;
        #pragma unroll
        for (int g = 0; g < 4; ++g) {
            int d0 = 8 * g + 4 * hi;
            ushort4 w0, w1;
            w0.x = f2bf(oB0[4 * g + 0] * inv);
            w0.y = f2bf(oB0[4 * g + 1] * inv);
            w0.z = f2bf(oB0[4 * g + 2] * inv);
            w0.w = f2bf(oB0[4 * g + 3] * inv);
            *(ushort4*)(obase + d0) = w0;
            w1.x = f2bf(oB1[4 * g + 0] * inv);
            w1.y = f2bf(oB1[4 * g + 1] * inv);
            w1.z = f2bf(oB1[4 * g + 2] * inv);
            w1.w = f2bf(oB1[4 * g + 3] * inv);
            *(ushort4*)(obase + 32 + d0) = w1;
        }
    }
}

// ---------------- launch ----------------
extern "C" void kernel_launch(void* const* d_in, const int* in_sizes, int n_in,
                              void* d_out, int out_size, void* d_ws, size_t ws_size,
                              hipStream_t stream) {
    (void)in_sizes; (void)n_in; (void)out_size; (void)ws_size;
    const float* x     = (const float*)d_in[0];
    const float* w_qkv = (const float*)d_in[1];
    const float* b_qkv = (const float*)d_in[2];
    const float* w_out = (const float*)d_in[3];
    const float* b_out = (const float*)d_in[4];

    unsigned short* ws = (unsigned short*)d_ws;
    unsigned short* xb    = ws;
    unsigned short* wqkvb = ws + 8388608;
    unsigned short* woutb = ws + 11534336;
    unsigned short* qkvb  = ws + 12582912;

    cvt_kernel<<<dim3(2048), dim3(256), 0, stream>>>(x, xb, 8388608 / 4);
    cvt_kernel<<<dim3(1024), dim3(256), 0, stream>>>(w_qkv, wqkvb, 3145728 / 4);
    cvt_kernel<<<dim3(512),  dim3(256), 0, stream>>>(w_out, woutb, 1048576 / 4);

    // QKV: M=8192 N=3072 K=1024 -> 64x12 = 768 blocks (3 exact rounds/CU)
    gemm256<0><<<dim3(768), dim3(512), 0, stream>>>(xb, wqkvb, b_qkv, (void*)qkvb, 8192, 3072, 1024, 12);

    attn_kernel<<<dim3(512), dim3(256), 0, stream>>>(qkvb, xb);

    // OUT: M=8192 N=1024 K=1024 -> 64x4 = 256 blocks (1/CU exactly)
    gemm256<1><<<dim3(256), dim3(512), 0, stream>>>(xb, woutb, b_out, d_out, 8192, 1024, 1024, 4);
}

// Round 13
// 176.108 us; speedup vs baseline: 1.0738x; 1.0738x over previous
//
#include <hip/hip_runtime.h>

typedef __bf16 bf16x8 __attribute__((ext_vector_type(8)));
typedef float f32x4 __attribute__((ext_vector_type(4)));
typedef float f32x16 __attribute__((ext_vector_type(16)));
typedef unsigned int uint2v __attribute__((ext_vector_type(2)));

#define LOG2E 1.44269504088896340736f

#if __has_builtin(__builtin_amdgcn_exp2f)
#define EXP2(x) __builtin_amdgcn_exp2f(x)
#else
#define EXP2(x) exp2f(x)
#endif

static __device__ __forceinline__ unsigned short f2bf(float f) {
    unsigned int u = __builtin_bit_cast(unsigned int, f);
    u += 0x7fffu + ((u >> 16) & 1u);   // RNE
    return (unsigned short)(u >> 16);
}

static __device__ __forceinline__ void plswap(unsigned int& a, unsigned int& b) {
#if __has_builtin(__builtin_amdgcn_permlane32_swap)
    uint2v r = __builtin_amdgcn_permlane32_swap(a, b, false, false);
    a = r.x; b = r.y;
#else
    asm("v_permlane32_swap_b32 %0, %1" : "+v"(a), "+v"(b));
#endif
}

static __device__ __forceinline__ float xhalf_add(float x) {
    unsigned int a = __builtin_bit_cast(unsigned int, x), b = a;
    plswap(a, b);
    return __builtin_bit_cast(float, a) + __builtin_bit_cast(float, b);
}

// ---------------- fused fp32 -> bf16 convert (x | w_qkv | w_out in one launch) ----------------
__global__ void cvt3_kernel(const float* __restrict__ x, const float* __restrict__ wq,
                            const float* __restrict__ wo,
                            unsigned short* __restrict__ xb, unsigned short* __restrict__ wqb,
                            unsigned short* __restrict__ wob) {
    // flat float4 index space: x 2097152 | w_qkv 786432 | w_out 262144 = 3145728
    int i = blockIdx.x * blockDim.x + threadIdx.x;
    int stride = gridDim.x * blockDim.x;
    for (; i < 3145728; i += stride) {
        const float* src;
        unsigned short* dst;
        int j;
        if (i < 2097152)      { j = i;           src = x;  dst = xb;  }
        else if (i < 2883584) { j = i - 2097152; src = wq; dst = wqb; }
        else                  { j = i - 2883584; src = wo; dst = wob; }
        float4 v = reinterpret_cast<const float4*>(src)[j];
        ushort4 o;
        o.x = f2bf(v.x); o.y = f2bf(v.y); o.z = f2bf(v.z); o.w = f2bf(v.w);
        reinterpret_cast<ushort4*>(dst)[j] = o;
    }
}

// ---------------- bf16 GEMM, C = A * B^T (+bias) — r9-proven 2-phase structure ----------------
template <int MODE>
__global__ __launch_bounds__(256, 2) void gemm_bt(const unsigned short* __restrict__ A,
                                                  const unsigned short* __restrict__ B,
                                                  const float* __restrict__ bias,
                                                  void* __restrict__ Cout,
                                                  int M, int N, int K) {
    __shared__ unsigned short SH[2][2][128 * 64];   // [buf][A/B][128x64] = 64 KB
    const int tid = threadIdx.x;
    const int w = tid >> 6, lane = tid & 63;
    const int wr = w >> 1, wc = w & 1;
    const int bm0 = blockIdx.y << 7, bn0 = blockIdx.x << 7;
    const int l15 = lane & 15, l4 = lane >> 4;

    const int srow = w * 8 + (lane >> 3);
    const int gch = (lane & 7) ^ (lane >> 3);

    f32x4 acc[4][4] = {};

    auto stage = [&](int buf, int kt) {
        const int k0 = kt << 6;
        #pragma unroll
        for (int i = 0; i < 4; ++i) {
            int row = i * 32 + srow;
            const unsigned short* ga = A + (size_t)(bm0 + row) * K + k0 + gch * 8;
            __builtin_amdgcn_global_load_lds(
                (const __attribute__((address_space(1))) void*)ga,
                (__attribute__((address_space(3))) void*)&SH[buf][0][i * 2048 + w * 512],
                16, 0, 0);
            const unsigned short* gb = B + (size_t)(bn0 + row) * K + k0 + gch * 8;
            __builtin_amdgcn_global_load_lds(
                (const __attribute__((address_space(1))) void*)gb,
                (__attribute__((address_space(3))) void*)&SH[buf][1][i * 2048 + w * 512],
                16, 0, 0);
        }
    };

    const int nk = K >> 6;
    stage(0, 0);
    __syncthreads();
    int buf = 0;
    for (int kt = 0; kt < nk; ++kt) {
        if (kt + 1 < nk) stage(buf ^ 1, kt + 1);
        const unsigned short* as = &SH[buf][0][0];
        const unsigned short* bs = &SH[buf][1][0];
        #pragma unroll
        for (int s = 0; s < 2; ++s) {
            bf16x8 af[4], bfr[4];
            #pragma unroll
            for (int t = 0; t < 4; ++t) {
                int rowa = wr * 64 + t * 16 + l15;
                int cha = (s * 4 + l4) ^ (rowa & 7);
                af[t] = *(const bf16x8*)&as[rowa * 64 + cha * 8];
                int rowb = wc * 64 + t * 16 + l15;
                int chb = (s * 4 + l4) ^ (rowb & 7);
                bfr[t] = *(const bf16x8*)&bs[rowb * 64 + chb * 8];
            }
            #pragma unroll
            for (int i = 0; i < 4; ++i)
                #pragma unroll
                for (int j = 0; j < 4; ++j)
                    acc[i][j] = __builtin_amdgcn_mfma_f32_16x16x32_bf16(af[i], bfr[j], acc[i][j], 0, 0, 0);
        }
        __syncthreads();
        buf ^= 1;
    }

    if (MODE == 0) {
        unsigned short* O = (unsigned short*)Cout;
        if (bn0 >= 2048) {
            // V region: LDS-bounce transpose -> coalesced uint4 stores
            unsigned short* T = &SH[0][0][0];
            __syncthreads();
            #pragma unroll
            for (int j = 0; j < 4; ++j) {
                int cl = wc * 64 + j * 16 + l15;
                float bv = bias[bn0 + cl];
                #pragma unroll
                for (int i = 0; i < 4; ++i) {
                    int nl = wr * 64 + i * 16 + l4 * 4;
                    ushort4 pk;
                    pk.x = f2bf(acc[i][j][0] + bv);
                    pk.y = f2bf(acc[i][j][1] + bv);
                    pk.z = f2bf(acc[i][j][2] + bv);
                    pk.w = f2bf(acc[i][j][3] + bv);
                    *(ushort4*)&T[cl * 136 + nl] = pk;
                }
            }
            __syncthreads();
            const int b = bm0 >> 11, n0 = bm0 & 2047;
            const int h0 = (bn0 >> 6) & 15;
            #pragma unroll
            for (int it = 0; it < 8; ++it) {
                int dl = it * 16 + (tid >> 4);
                int ch = tid & 15;
                uint4 val = *(const uint4*)&T[dl * 136 + ch * 8];
                size_t idx = (size_t)16777216 +
                             ((size_t)((b * 16 + (h0 + (dl >> 6))) * 64 + (dl & 63))) * 2048 +
                             n0 + ch * 8;
                *(uint4*)&O[idx] = val;
            }
        } else {
            #pragma unroll
            for (int j = 0; j < 4; ++j) {
                int col = bn0 + wc * 64 + j * 16 + l15;
                float bv = bias[col];
                int which = col >> 10;
                int h = (col >> 6) & 15;
                int d = col & 63;
                #pragma unroll
                for (int i = 0; i < 4; ++i) {
                    #pragma unroll
                    for (int r = 0; r < 4; ++r) {
                        int row = bm0 + wr * 64 + i * 16 + l4 * 4 + r;
                        int b = row >> 11, n = row & 2047;
                        float v = acc[i][j][r] + bv;
                        size_t idx;
                        if (which == 0) { v *= 0.125f * LOG2E; idx = ((size_t)((b * 16 + h) * 2048 + n)) * 64 + d; }
                        else { idx = (size_t)8388608 + ((size_t)((b * 16 + h) * 2048 + n)) * 64 + d; }
                        O[idx] = f2bf(v);
                    }
                }
            }
        }
    } else {
        float* C = (float*)Cout;
        #pragma unroll
        for (int j = 0; j < 4; ++j) {
            int col = bn0 + wc * 64 + j * 16 + l15;
            float bv = bias[col];
            #pragma unroll
            for (int i = 0; i < 4; ++i) {
                #pragma unroll
                for (int r = 0; r < 4; ++r) {
                    int row = bm0 + wr * 64 + i * 16 + l4 * 4 + r;
                    C[(size_t)row * N + col] = acc[i][j][r] + bv;
                }
            }
        }
    }
}

// ---------------- flash attention v7 (r9-proven): 64 q/wave, no online max ----------------
__global__ __launch_bounds__(256, 2) void attn_kernel(const unsigned short* __restrict__ qkv,
                                                      unsigned short* __restrict__ out) {
    __shared__ unsigned short Klds[2][4096];   // [64 k-rows][64 d]
    __shared__ unsigned short Vlds[2][4096];   // [64 d-rows][64 n]

    const int tid = threadIdx.x;
    const int w = tid >> 6, lane = tid & 63;
    const int ql = lane & 31;
    const int hi = lane >> 5;
    const int id = blockIdx.x;       // 0..511
    const int bh = id & 63;          // all 8 q-tiles of a head land on one XCD
    const int qt = id >> 6;          // 0..7
    const size_t SEC = 8388608;

    const unsigned short* Q  = qkv + (size_t)bh * (2048 * 64);
    const unsigned short* Kp = qkv + SEC + (size_t)bh * (2048 * 64);
    const unsigned short* Vt = qkv + 2 * SEC + (size_t)bh * (64 * 2048);

    const int q0 = qt * 256 + w * 64;

    bf16x8 qbA[4], qbB[4];
    #pragma unroll
    for (int c = 0; c < 4; ++c) {
        qbA[c] = *(const bf16x8*)&Q[(size_t)(q0 + ql) * 64 + c * 16 + hi * 8];
        qbB[c] = *(const bf16x8*)&Q[(size_t)(q0 + 32 + ql) * 64 + c * 16 + hi * 8];
    }

    f32x16 oA0 = {}, oA1 = {}, oB0 = {}, oB1 = {};
    float lsA = 0.f, lsB = 0.f;

    const int sri = lane >> 3;
    const int sch = lane & 7;

    auto stage = [&](int buf, int tile) {
        const int kb = tile * 64;
        #pragma unroll
        for (int i = 0; i < 2; ++i) {
            const int r = w * 16 + i * 8 + sri;
            const int c = sch ^ (r & 7);
            const unsigned short* gk = Kp + (size_t)(kb + r) * 64 + c * 8;
            __builtin_amdgcn_global_load_lds(
                (const __attribute__((address_space(1))) void*)gk,
                (__attribute__((address_space(3))) void*)&Klds[buf][w * 1024 + i * 512],
                16, 0, 0);
            const unsigned short* gv = Vt + (size_t)r * 2048 + kb + c * 8;
            __builtin_amdgcn_global_load_lds(
                (const __attribute__((address_space(1))) void*)gv,
                (__attribute__((address_space(3))) void*)&Vlds[buf][w * 1024 + i * 512],
                16, 0, 0);
        }
    };

    auto softmax_block = [&](f32x16& s0, f32x16& s1, float& lsum,
                             bf16x8 (&p0)[2], bf16x8 (&p1)[2]) {
        #pragma unroll
        for (int r = 0; r < 16; ++r) s0[r] = EXP2(s0[r]);
        #pragma unroll
        for (int r = 0; r < 16; ++r) s1[r] = EXP2(s1[r]);
        float u0 = ((s0[0] + s0[1]) + (s0[2] + s0[3])) + ((s0[4] + s0[5]) + (s0[6] + s0[7]));
        float u1 = ((s0[8] + s0[9]) + (s0[10] + s0[11])) + ((s0[12] + s0[13]) + (s0[14] + s0[15]));
        float u2 = ((s1[0] + s1[1]) + (s1[2] + s1[3])) + ((s1[4] + s1[5]) + (s1[6] + s1[7]));
        float u3 = ((s1[8] + s1[9]) + (s1[10] + s1[11])) + ((s1[12] + s1[13]) + (s1[14] + s1[15]));
        float rs = (u0 + u1) + (u2 + u3);
        lsum += xhalf_add(rs);
        #pragma unroll
        for (int g = 0; g < 2; ++g) {
            unsigned int x0, x1, x2, x3;
            asm("v_cvt_pk_bf16_f32 %0, %1, %2" : "=v"(x0) : "v"(s0[8*g + 0]), "v"(s0[8*g + 1]));
            asm("v_cvt_pk_bf16_f32 %0, %1, %2" : "=v"(x1) : "v"(s0[8*g + 2]), "v"(s0[8*g + 3]));
            asm("v_cvt_pk_bf16_f32 %0, %1, %2" : "=v"(x2) : "v"(s0[8*g + 4]), "v"(s0[8*g + 5]));
            asm("v_cvt_pk_bf16_f32 %0, %1, %2" : "=v"(x3) : "v"(s0[8*g + 6]), "v"(s0[8*g + 7]));
            plswap(x0, x2);
            plswap(x1, x3);
            uint4 wds; wds.x = x0; wds.y = x1; wds.z = x2; wds.w = x3;
            p0[g] = __builtin_bit_cast(bf16x8, wds);
        }
        #pragma unroll
        for (int g = 0; g < 2; ++g) {
            unsigned int x0, x1, x2, x3;
            asm("v_cvt_pk_bf16_f32 %0, %1, %2" : "=v"(x0) : "v"(s1[8*g + 0]), "v"(s1[8*g + 1]));
            asm("v_cvt_pk_bf16_f32 %0, %1, %2" : "=v"(x1) : "v"(s1[8*g + 2]), "v"(s1[8*g + 3]));
            asm("v_cvt_pk_bf16_f32 %0, %1, %2" : "=v"(x2) : "v"(s1[8*g + 4]), "v"(s1[8*g + 5]));
            asm("v_cvt_pk_bf16_f32 %0, %1, %2" : "=v"(x3) : "v"(s1[8*g + 6]), "v"(s1[8*g + 7]));
            plswap(x0, x2);
            plswap(x1, x3);
            uint4 wds; wds.x = x0; wds.y = x1; wds.z = x2; wds.w = x3;
            p1[g] = __builtin_bit_cast(bf16x8, wds);
        }
    };

    stage(0, 0);
    __syncthreads();

    for (int t = 0; t < 32; ++t) {
        const int cur = t & 1;
        if (t + 1 < 32) stage(cur ^ 1, t + 1);

        bf16x8 k0[4], k1[4];
        #pragma unroll
        for (int mf = 0; mf < 4; ++mf) {
            int c0 = ((mf * 2 + hi) ^ (ql & 7));
            k0[mf] = *(const bf16x8*)&Klds[cur][ql * 64 + c0 * 8];
            k1[mf] = *(const bf16x8*)&Klds[cur][(32 + ql) * 64 + c0 * 8];
        }

        f32x16 sA0 = {}, sA1 = {};
        #pragma unroll
        for (int mf = 0; mf < 4; ++mf)
            sA0 = __builtin_amdgcn_mfma_f32_32x32x16_bf16(k0[mf], qbA[mf], sA0, 0, 0, 0);
        #pragma unroll
        for (int mf = 0; mf < 4; ++mf)
            sA1 = __builtin_amdgcn_mfma_f32_32x32x16_bf16(k1[mf], qbA[mf], sA1, 0, 0, 0);
        f32x16 sB0 = {}, sB1 = {};
        #pragma unroll
        for (int mf = 0; mf < 4; ++mf)
            sB0 = __builtin_amdgcn_mfma_f32_32x32x16_bf16(k0[mf], qbB[mf], sB0, 0, 0, 0);
        #pragma unroll
        for (int mf = 0; mf < 4; ++mf)
            sB1 = __builtin_amdgcn_mfma_f32_32x32x16_bf16(k1[mf], qbB[mf], sB1, 0, 0, 0);

        bf16x8 v0[4], v1[4];
        #pragma unroll
        for (int ks = 0; ks < 4; ++ks) {
            int c0 = ((ks * 2 + hi) ^ (ql & 7));
            v0[ks] = *(const bf16x8*)&Vlds[cur][ql * 64 + c0 * 8];
            v1[ks] = *(const bf16x8*)&Vlds[cur][(32 + ql) * 64 + c0 * 8];
        }

        bf16x8 pA0[2], pA1[2], pB0[2], pB1[2];
        softmax_block(sA0, sA1, lsA, pA0, pA1);
        softmax_block(sB0, sB1, lsB, pB0, pB1);

        oA0 = __builtin_amdgcn_mfma_f32_32x32x16_bf16(v0[0], pA0[0], oA0, 0, 0, 0);
        oA0 = __builtin_amdgcn_mfma_f32_32x32x16_bf16(v0[1], pA0[1], oA0, 0, 0, 0);
        oA0 = __builtin_amdgcn_mfma_f32_32x32x16_bf16(v0[2], pA1[0], oA0, 0, 0, 0);
        oA0 = __builtin_amdgcn_mfma_f32_32x32x16_bf16(v0[3], pA1[1], oA0, 0, 0, 0);
        oA1 = __builtin_amdgcn_mfma_f32_32x32x16_bf16(v1[0], pA0[0], oA1, 0, 0, 0);
        oA1 = __builtin_amdgcn_mfma_f32_32x32x16_bf16(v1[1], pA0[1], oA1, 0, 0, 0);
        oA1 = __builtin_amdgcn_mfma_f32_32x32x16_bf16(v1[2], pA1[0], oA1, 0, 0, 0);
        oA1 = __builtin_amdgcn_mfma_f32_32x32x16_bf16(v1[3], pA1[1], oA1, 0, 0, 0);
        oB0 = __builtin_amdgcn_mfma_f32_32x32x16_bf16(v0[0], pB0[0], oB0, 0, 0, 0);
        oB0 = __builtin_amdgcn_mfma_f32_32x32x16_bf16(v0[1], pB0[1], oB0, 0, 0, 0);
        oB0 = __builtin_amdgcn_mfma_f32_32x32x16_bf16(v0[2], pB1[0], oB0, 0, 0, 0);
        oB0 = __builtin_amdgcn_mfma_f32_32x32x16_bf16(v0[3], pB1[1], oB0, 0, 0, 0);
        oB1 = __builtin_amdgcn_mfma_f32_32x32x16_bf16(v1[0], pB0[0], oB1, 0, 0, 0);
        oB1 = __builtin_amdgcn_mfma_f32_32x32x16_bf16(v1[1], pB0[1], oB1, 0, 0, 0);
        oB1 = __builtin_amdgcn_mfma_f32_32x32x16_bf16(v1[2], pB1[0], oB1, 0, 0, 0);
        oB1 = __builtin_amdgcn_mfma_f32_32x32x16_bf16(v1[3], pB1[1], oB1, 0, 0, 0);

        __syncthreads();
    }

    const int b = bh >> 4, h = bh & 15;
    {
        const float inv = 1.0f / lsA;
        const int n = q0 + ql;
        unsigned short* obase = out + ((size_t)(b * 2048 + n)) * 1024 + h * 64;
        #pragma unroll
        for (int g = 0; g < 4; ++g) {
            int d0 = 8 * g + 4 * hi;
            ushort4 w0, w1;
            w0.x = f2bf(oA0[4 * g + 0] * inv);
            w0.y = f2bf(oA0[4 * g + 1] * inv);
            w0.z = f2bf(oA0[4 * g + 2] * inv);
            w0.w = f2bf(oA0[4 * g + 3] * inv);
            *(ushort4*)(obase + d0) = w0;
            w1.x = f2bf(oA1[4 * g + 0] * inv);
            w1.y = f2bf(oA1[4 * g + 1] * inv);
            w1.z = f2bf(oA1[4 * g + 2] * inv);
            w1.w = f2bf(oA1[4 * g + 3] * inv);
            *(ushort4*)(obase + 32 + d0) = w1;
        }
    }
    {
        const float inv = 1.0f / lsB;
        const int n = q0 + 32 + ql;
        unsigned short* obase = out + ((size_t)(b * 2048 + n)) * 1024 + h * 64;
        #pragma unroll
        for (int g = 0; g < 4; ++g) {
            int d0 = 8 * g + 4 * hi;
            ushort4 w0, w1;
            w0.x = f2bf(oB0[4 * g + 0] * inv);
            w0.y = f2bf(oB0[4 * g + 1] * inv);
            w0.z = f2bf(oB0[4 * g + 2] * inv);
            w0.w = f2bf(oB0[4 * g + 3] * inv);
            *(ushort4*)(obase + d0) = w0;
            w1.x = f2bf(oB1[4 * g + 0] * inv);
            w1.y = f2bf(oB1[4 * g + 1] * inv);
            w1.z = f2bf(oB1[4 * g + 2] * inv);
            w1.w = f2bf(oB1[4 * g + 3] * inv);
            *(ushort4*)(obase + 32 + d0) = w1;
        }
    }
}

// ---------------- launch ----------------
extern "C" void kernel_launch(void* const* d_in, const int* in_sizes, int n_in,
                              void* d_out, int out_size, void* d_ws, size_t ws_size,
                              hipStream_t stream) {
    (void)in_sizes; (void)n_in; (void)out_size; (void)ws_size;
    const float* x     = (const float*)d_in[0];
    const float* w_qkv = (const float*)d_in[1];
    const float* b_qkv = (const float*)d_in[2];
    const float* w_out = (const float*)d_in[3];
    const float* b_out = (const float*)d_in[4];

    unsigned short* ws = (unsigned short*)d_ws;
    unsigned short* xb    = ws;
    unsigned short* wqkvb = ws + 8388608;
    unsigned short* woutb = ws + 11534336;
    unsigned short* qkvb  = ws + 12582912;

    cvt3_kernel<<<dim3(2048), dim3(256), 0, stream>>>(x, w_qkv, w_out, xb, wqkvb, woutb);

    gemm_bt<0><<<dim3(24, 64), dim3(256), 0, stream>>>(xb, wqkvb, b_qkv, (void*)qkvb, 8192, 3072, 1024);

    attn_kernel<<<dim3(512), dim3(256), 0, stream>>>(qkvb, xb);

    gemm_bt<1><<<dim3(8, 64), dim3(256), 0, stream>>>(xb, woutb, b_out, d_out, 8192, 1024, 1024);
}